// Round 4
// baseline (297.219 us; speedup 1.0000x reference)
//
#include <hip/hip_runtime.h>
#include <math.h>

// TopKGate: logits = x @ W^T ; softmax ; top-2 ; scatter weights + indices(float).
// x: [8192,4096] f32, W: [64,4096] f32.
// d_out (f32 flat): weights [8192*64] then indices [8192*2] as floats.
//
// lane = expert (W chunk double-buffered in VGPRs); x loads forced to VMEM
// (in-order, vmcnt-pipelined) via an opaque VGPR zero in the address.

#define TOKENS 8192
#define DIM    4096
#define NEXP   64

#define TBLK   32                    // tokens per block
#define BWAVES 8                     // waves per block
#define KB     2                     // k-split across blocks
#define KSEG   (DIM / KB / BWAVES)   // 256 k per wave
#define KC     16                    // W chunk held in VGPRs
#define NCH    (KSEG / KC)           // 16 chunks

__global__ __launch_bounds__(512, 4)
void tg_main(const float* __restrict__ x, const float* __restrict__ W,
             float* __restrict__ part)
{
    __shared__ float rbuf[4][TBLK * NEXP];   // 4 x 8 KB reduce buffers

    const int tid  = threadIdx.x;
    const int lane = tid & 63;                                   // = expert
    const int wave = __builtin_amdgcn_readfirstlane(tid >> 6);
    const int tg   = blockIdx.x >> 1;        // token group 0..255
    const int kb   = blockIdx.x & 1;         // k half
    const int tok0 = tg * TBLK;
    const int k0   = kb * (DIM / KB) + wave * KSEG;

    // opaque zero living in a VGPR: defeats uniformity analysis so x loads
    // stay VMEM (in-order, counted vmcnt) instead of out-of-order SMEM
    int vzero = 0;
    asm volatile("" : "+v"(vzero));

    float acc[TBLK];
#pragma unroll
    for (int t = 0; t < TBLK; ++t) acc[t] = 0.0f;

    const float* wrow  = W + (size_t)lane * DIM + k0;          // per-lane row
    const float* xbase = x + (size_t)tok0 * DIM + k0 + vzero;  // vector addr

    auto loadw = [&](float4 (&wv)[KC / 4], int c) {
#pragma unroll
        for (int i = 0; i < KC / 4; ++i)
            wv[i] = *reinterpret_cast<const float4*>(wrow + c * KC + 4 * i);
    };
    auto step = [&](const float4 (&wv)[KC / 4], int c) {
        const float* xc = xbase + c * KC;
#pragma unroll 8
        for (int t = 0; t < TBLK; ++t) {
            const float* xr = xc + (size_t)t * DIM;
            const float4 x0 = *reinterpret_cast<const float4*>(xr + 0);
            const float4 x1 = *reinterpret_cast<const float4*>(xr + 4);
            const float4 x2 = *reinterpret_cast<const float4*>(xr + 8);
            const float4 x3 = *reinterpret_cast<const float4*>(xr + 12);
            acc[t] = fmaf(x0.x, wv[0].x, acc[t]);
            acc[t] = fmaf(x0.y, wv[0].y, acc[t]);
            acc[t] = fmaf(x0.z, wv[0].z, acc[t]);
            acc[t] = fmaf(x0.w, wv[0].w, acc[t]);
            acc[t] = fmaf(x1.x, wv[1].x, acc[t]);
            acc[t] = fmaf(x1.y, wv[1].y, acc[t]);
            acc[t] = fmaf(x1.z, wv[1].z, acc[t]);
            acc[t] = fmaf(x1.w, wv[1].w, acc[t]);
            acc[t] = fmaf(x2.x, wv[2].x, acc[t]);
            acc[t] = fmaf(x2.y, wv[2].y, acc[t]);
            acc[t] = fmaf(x2.z, wv[2].z, acc[t]);
            acc[t] = fmaf(x2.w, wv[2].w, acc[t]);
            acc[t] = fmaf(x3.x, wv[3].x, acc[t]);
            acc[t] = fmaf(x3.y, wv[3].y, acc[t]);
            acc[t] = fmaf(x3.z, wv[3].z, acc[t]);
            acc[t] = fmaf(x3.w, wv[3].w, acc[t]);
        }
    };

    // double-buffered W chunks: refill latency hides under 512 FMAs/chunk
    float4 wa[KC / 4], wb[KC / 4];
    loadw(wa, 0);
#pragma unroll 2
    for (int c = 0; c < NCH; c += 2) {
        loadw(wb, c + 1);
        step(wa, c);
        if (c + 2 < NCH) loadw(wa, c + 2);
        step(wb, c + 1);
    }

    // ---- deterministic 8-wave tree reduction (8 -> 4 -> 2 -> 1) ----
    auto dump = [&](int b) {
        float* buf = &rbuf[b][0];
#pragma unroll
        for (int t = 0; t < TBLK; ++t) buf[t * NEXP + lane] = acc[t];
    };
    auto fold = [&](int b) {
        const float* buf = &rbuf[b][0];
#pragma unroll
        for (int t = 0; t < TBLK; ++t) acc[t] += buf[t * NEXP + lane];
    };

    if (wave >= 4) dump(wave - 4);
    __syncthreads();
    if (wave < 4) fold(wave);
    __syncthreads();
    if (wave == 2 || wave == 3) dump(wave - 2);
    __syncthreads();
    if (wave < 2) fold(wave);
    __syncthreads();
    if (wave == 1) dump(0);
    __syncthreads();
    if (wave == 0) {
        fold(0);
        float* dst = part + ((size_t)kb * TOKENS + tok0) * NEXP;
#pragma unroll
        for (int t = 0; t < TBLK; ++t) dst[t * NEXP + lane] = acc[t];
    }
}

// ---------- finalize: combine k-halves, softmax, top-2, scatter ----------
__global__ void tg_final(const float* __restrict__ part,
                         float* __restrict__ out_w, float* __restrict__ out_i)
{
    int t = blockIdx.x * blockDim.x + threadIdx.x;   // 0..8191
    const float* p0 = part + (size_t)t * NEXP;
    const float* p1 = part + (size_t)(TOKENS + t) * NEXP;

    float lg[NEXP];
    float m = -1e30f;
#pragma unroll
    for (int e = 0; e < NEXP; e += 4) {
        float4 a = *reinterpret_cast<const float4*>(p0 + e);
        float4 b = *reinterpret_cast<const float4*>(p1 + e);
        lg[e+0] = a.x + b.x; lg[e+1] = a.y + b.y;
        lg[e+2] = a.z + b.z; lg[e+3] = a.w + b.w;
        m = fmaxf(m, fmaxf(fmaxf(lg[e+0], lg[e+1]), fmaxf(lg[e+2], lg[e+3])));
    }
    float s = 0.0f;
#pragma unroll
    for (int e = 0; e < NEXP; ++e) { lg[e] = expf(lg[e] - m); s += lg[e]; }
    float inv = 1.0f / s;

    // top-2 on probs; strict '>' scan => lower index wins ties (jax order)
    float v1 = -1.0f, v2 = -1.0f; int i1 = 0, i2 = 0;
#pragma unroll
    for (int e = 0; e < NEXP; ++e) {
        float p = lg[e] * inv;
        lg[e] = p;
        if (p > v1)      { v2 = v1; i2 = i1; v1 = p; i1 = e; }
        else if (p > v2) { v2 = p; i2 = e; }
    }

    float* dst = out_w + (size_t)t * NEXP;
#pragma unroll
    for (int e = 0; e < NEXP; e += 4) {
        float4 o;
        o.x = (e+0 == i1) ? v1 : (e+0 == i2) ? v2 : 0.0f;
        o.y = (e+1 == i1) ? v1 : (e+1 == i2) ? v2 : 0.0f;
        o.z = (e+2 == i1) ? v1 : (e+2 == i2) ? v2 : 0.0f;
        o.w = (e+3 == i1) ? v1 : (e+3 == i2) ? v2 : 0.0f;
        *reinterpret_cast<float4*>(dst + e) = o;
    }
    out_i[(size_t)t * 2 + 0] = (float)i1;
    out_i[(size_t)t * 2 + 1] = (float)i2;
}

extern "C" void kernel_launch(void* const* d_in, const int* in_sizes, int n_in,
                              void* d_out, int out_size, void* d_ws, size_t ws_size,
                              hipStream_t stream) {
    const float* x = (const float*)d_in[0];
    const float* W = (const float*)d_in[1];
    float* out_w = (float*)d_out;
    float* out_i = out_w + (size_t)TOKENS * NEXP;

    float* part = (float*)d_ws;   // KB * 8192 * 64 f32 = 4 MB

    tg_main <<<dim3(TOKENS / TBLK * KB), dim3(512), 0, stream>>>(x, W, part);
    tg_final<<<dim3(TOKENS / 256), dim3(256), 0, stream>>>(part, out_w, out_i);
}

// Round 5
// 88.945 us; speedup vs baseline: 3.3416x; 3.3416x over previous
//
#include <hip/hip_runtime.h>
#include <math.h>

// TopKGate: logits = x @ W^T ; softmax ; top-2 ; scatter weights + indices(float).
// x: [8192,4096] f32, W: [64,4096] f32.
// d_out (f32 flat): weights [8192*64] then indices [8192*2] as floats.
//
// Classic LDS-tiled SGEMM: BM=64 tok x BN=64 exp x BK=32, 256 threads,
// 4x4 thread tile, per-lane ds_read_b128 (no broadcast operands),
// reg-staged transposed LDS tiles, double-buffered, KSPLIT=4 for occupancy.

#define TOKENS 8192
#define DIM    4096
#define NEXP   64

#define BM     64
#define BK     32
#define KSPLIT 4
#define KSEG   (DIM / KSPLIT)   // 1024
#define NKT    (KSEG / BK)      // 32 k-tiles
#define PITCH  68               // LDS row pitch (floats): 272 B, 16B-aligned

__global__ __launch_bounds__(256, 4)
void tg_main(const float* __restrict__ x, const float* __restrict__ W,
             float* __restrict__ part)
{
    __shared__ float xs[2][BK][PITCH];   // x tile, transposed: xs[k][token]
    __shared__ float ws[2][BK][PITCH];   // W tile, transposed: ws[k][expert]

    const int tid = threadIdx.x;
    const int mb  = blockIdx.x >> 2;     // token group 0..127
    const int ks  = blockIdx.x & 3;      // k split 0..3
    const int t0  = mb * BM;
    const int k0  = ks * KSEG;

    // staging mapping: 4 lanes per row, each loads 32 B (2 float4)
    const int tr = tid >> 2;             // row 0..63 (token for x, expert for W)
    const int ko = (tid & 3) * 8;        // k offset 0,8,16,24

    const float* xg = x + (size_t)(t0 + tr) * DIM + k0 + ko;
    const float* wg = W + (size_t)tr * DIM + k0 + ko;

    // compute mapping: thread owns tokens 4*tg..+3, experts 4*eg..+3
    const int tg = tid & 15;
    const int eg = tid >> 4;

    float acc[4][4];
#pragma unroll
    for (int i = 0; i < 4; ++i)
#pragma unroll
        for (int j = 0; j < 4; ++j) acc[i][j] = 0.0f;

    float4 rx0, rx1, rw0, rw1;
    auto issue = [&](int kt) {
        const float* xp = xg + kt * BK;
        const float* wp = wg + kt * BK;
        rx0 = *reinterpret_cast<const float4*>(xp);
        rx1 = *reinterpret_cast<const float4*>(xp + 4);
        rw0 = *reinterpret_cast<const float4*>(wp);
        rw1 = *reinterpret_cast<const float4*>(wp + 4);
    };
    auto commit = [&](int b) {
        xs[b][ko + 0][tr] = rx0.x; xs[b][ko + 1][tr] = rx0.y;
        xs[b][ko + 2][tr] = rx0.z; xs[b][ko + 3][tr] = rx0.w;
        xs[b][ko + 4][tr] = rx1.x; xs[b][ko + 5][tr] = rx1.y;
        xs[b][ko + 6][tr] = rx1.z; xs[b][ko + 7][tr] = rx1.w;
        ws[b][ko + 0][tr] = rw0.x; ws[b][ko + 1][tr] = rw0.y;
        ws[b][ko + 2][tr] = rw0.z; ws[b][ko + 3][tr] = rw0.w;
        ws[b][ko + 4][tr] = rw1.x; ws[b][ko + 5][tr] = rw1.y;
        ws[b][ko + 6][tr] = rw1.z; ws[b][ko + 7][tr] = rw1.w;
    };

    // prologue: stage tile 0
    issue(0);
    commit(0);
    __syncthreads();

    for (int kt = 0; kt < NKT; ++kt) {
        const int p = kt & 1;
        const bool more = (kt + 1 < NKT);
        if (more) issue(kt + 1);          // HBM latency hides under compute

#pragma unroll
        for (int k = 0; k < BK; ++k) {
            const float4 xq = *reinterpret_cast<const float4*>(&xs[p][k][4 * tg]);
            const float4 wq = *reinterpret_cast<const float4*>(&ws[p][k][4 * eg]);
            acc[0][0] = fmaf(xq.x, wq.x, acc[0][0]);
            acc[0][1] = fmaf(xq.x, wq.y, acc[0][1]);
            acc[0][2] = fmaf(xq.x, wq.z, acc[0][2]);
            acc[0][3] = fmaf(xq.x, wq.w, acc[0][3]);
            acc[1][0] = fmaf(xq.y, wq.x, acc[1][0]);
            acc[1][1] = fmaf(xq.y, wq.y, acc[1][1]);
            acc[1][2] = fmaf(xq.y, wq.z, acc[1][2]);
            acc[1][3] = fmaf(xq.y, wq.w, acc[1][3]);
            acc[2][0] = fmaf(xq.z, wq.x, acc[2][0]);
            acc[2][1] = fmaf(xq.z, wq.y, acc[2][1]);
            acc[2][2] = fmaf(xq.z, wq.z, acc[2][2]);
            acc[2][3] = fmaf(xq.z, wq.w, acc[2][3]);
            acc[3][0] = fmaf(xq.w, wq.x, acc[3][0]);
            acc[3][1] = fmaf(xq.w, wq.y, acc[3][1]);
            acc[3][2] = fmaf(xq.w, wq.z, acc[3][2]);
            acc[3][3] = fmaf(xq.w, wq.w, acc[3][3]);
        }

        if (more) commit(p ^ 1);          // vmcnt wait lands here, post-compute
        __syncthreads();                  // one barrier per tile (dbuf)
    }

    // each block writes a full 64x64 partial for its k-range: no reduction
    float* dst = part + ((size_t)ks * TOKENS + t0 + 4 * tg) * NEXP + 4 * eg;
#pragma unroll
    for (int i = 0; i < 4; ++i) {
        float4 o = make_float4(acc[i][0], acc[i][1], acc[i][2], acc[i][3]);
        *reinterpret_cast<float4*>(dst + (size_t)i * NEXP) = o;
    }
}

// ---------- finalize: sum 4 k-split partials, softmax, top-2, scatter ----------
__global__ void tg_final(const float* __restrict__ part,
                         float* __restrict__ out_w, float* __restrict__ out_i)
{
    int t = blockIdx.x * blockDim.x + threadIdx.x;   // 0..8191

    float lg[NEXP];
    float m = -1e30f;
#pragma unroll
    for (int e = 0; e < NEXP; e += 4) {
        float4 a = *reinterpret_cast<const float4*>(part + (size_t)t * NEXP + e);
        float4 b = *reinterpret_cast<const float4*>(part + ((size_t)TOKENS + t) * NEXP + e);
        float4 c = *reinterpret_cast<const float4*>(part + ((size_t)2 * TOKENS + t) * NEXP + e);
        float4 d = *reinterpret_cast<const float4*>(part + ((size_t)3 * TOKENS + t) * NEXP + e);
        lg[e+0] = (a.x + b.x) + (c.x + d.x);
        lg[e+1] = (a.y + b.y) + (c.y + d.y);
        lg[e+2] = (a.z + b.z) + (c.z + d.z);
        lg[e+3] = (a.w + b.w) + (c.w + d.w);
        m = fmaxf(m, fmaxf(fmaxf(lg[e+0], lg[e+1]), fmaxf(lg[e+2], lg[e+3])));
    }
    float s = 0.0f;
#pragma unroll
    for (int e = 0; e < NEXP; ++e) { lg[e] = expf(lg[e] - m); s += lg[e]; }
    float inv = 1.0f / s;

    // top-2 on probs; strict '>' scan => lower index wins ties (jax order)
    float v1 = -1.0f, v2 = -1.0f; int i1 = 0, i2 = 0;
#pragma unroll
    for (int e = 0; e < NEXP; ++e) {
        float p = lg[e] * inv;
        lg[e] = p;
        if (p > v1)      { v2 = v1; i2 = i1; v1 = p; i1 = e; }
        else if (p > v2) { v2 = p; i2 = e; }
    }

    float* dst = out_w + (size_t)t * NEXP;
#pragma unroll
    for (int e = 0; e < NEXP; e += 4) {
        float4 o;
        o.x = (e+0 == i1) ? v1 : (e+0 == i2) ? v2 : 0.0f;
        o.y = (e+1 == i1) ? v1 : (e+1 == i2) ? v2 : 0.0f;
        o.z = (e+2 == i1) ? v1 : (e+2 == i2) ? v2 : 0.0f;
        o.w = (e+3 == i1) ? v1 : (e+3 == i2) ? v2 : 0.0f;
        *reinterpret_cast<float4*>(dst + e) = o;
    }
    out_i[(size_t)t * 2 + 0] = (float)i1;
    out_i[(size_t)t * 2 + 1] = (float)i2;
}

extern "C" void kernel_launch(void* const* d_in, const int* in_sizes, int n_in,
                              void* d_out, int out_size, void* d_ws, size_t ws_size,
                              hipStream_t stream) {
    const float* x = (const float*)d_in[0];
    const float* W = (const float*)d_in[1];
    float* out_w = (float*)d_out;
    float* out_i = out_w + (size_t)TOKENS * NEXP;

    float* part = (float*)d_ws;   // KSPLIT * 8192 * 64 f32 = 8 MB

    tg_main <<<dim3(TOKENS / BM * KSPLIT), dim3(256), 0, stream>>>(x, W, part);
    tg_final<<<dim3(TOKENS / 256), dim3(256), 0, stream>>>(part, out_w, out_i);
}

// Round 6
// 72.308 us; speedup vs baseline: 4.1105x; 1.2301x over previous
//
#include <hip/hip_runtime.h>
#include <math.h>

// TopKGate: logits = x @ W^T ; softmax ; top-2 ; scatter weights + indices(float).
// x: [8192,4096] f32, W: [64,4096] f32.
// d_out (f32 flat): weights [8192*64] then indices [8192*2] as floats.
//
// MFMA path: f32 emulated as bf16 hi/lo split (4 passes hh+hl+lh+ll),
// logit error ~3e-5 (random-sign cancellation over K=4096).
// No LDS, no barriers: A-frags straight from global (converted in regs),
// B-frags pre-packed fragment-ordered by a prep kernel (1 MB, L2-hot).
// k-slot consistency trick: A and B filled with the same k-map f(g,j)=g*8+j,
// so the hardware's internal slot order cancels.

#define TOKENS 8192
#define DIM    4096
#define NEXP   64
#define NCHW   (DIM / 32)          // 128 global k-chunks
#define FRAGS  ((size_t)NCHW * 4 * 64 * 8)   // 262144 shorts per array

typedef __attribute__((ext_vector_type(8))) short  short8;
typedef __attribute__((ext_vector_type(4))) float  f32x4;
typedef __attribute__((ext_vector_type(8))) float  f32x8;

__device__ __forceinline__ void bf16split(float v, short& hi, short& lo) {
    unsigned u = __float_as_uint(v);
    hi = (short)(u >> 16);
    float r = v - __uint_as_float(u & 0xffff0000u);
    lo = (short)(__float_as_uint(r) >> 16);
}

// ---- prep: W[64][4096] -> fragment-ordered bf16 hi/lo ----
// Whf[((c*4+nt)*64+lane)*8 + j] = bf16hi(W[e][k]), e = nt*16+(lane&15),
// k = c*32 + (lane>>4)*8 + j.
__global__ void tg_prepw(const float* __restrict__ W,
                         short* __restrict__ Whf, short* __restrict__ Wlf) {
    int gid  = blockIdx.x * 256 + threadIdx.x;   // 32768 threads
    int c    = gid >> 8, rem = gid & 255;
    int nt   = rem >> 6, lane = rem & 63;
    int e    = nt * 16 + (lane & 15);
    int kb   = c * 32 + (lane >> 4) * 8;
    const float* wp = W + (size_t)e * DIM + kb;
    short8 h, l;
#pragma unroll
    for (int j = 0; j < 8; ++j) {
        short hh, ll;
        bf16split(wp[j], hh, ll);
        h[j] = hh; l[j] = ll;
    }
    size_t o = ((size_t)(c * 4 + nt) * 64 + lane) * 8;
    *reinterpret_cast<short8*>(Whf + o) = h;
    *reinterpret_cast<short8*>(Wlf + o) = l;
}

// ---- main: per wave 16 tokens x 64 experts, k-range KSEG ----
template<int KS>
__global__ __launch_bounds__(256, 4)
void tg_mfma(const float* __restrict__ x,
             const short* __restrict__ Whf, const short* __restrict__ Wlf,
             float* __restrict__ part) {
    constexpr int KSEG = DIM / KS;
    constexpr int NCH  = KSEG / 32;
    const int lane = threadIdx.x & 63;
    const int wave = threadIdx.x >> 6;
    const int mb   = blockIdx.x / KS;
    const int ks   = blockIdx.x % KS;
    const int t0   = mb * 64 + wave * 16;
    const int row  = lane & 15;          // A row (token) / B,D col (expert)
    const int grp  = lane >> 4;
    const int k0   = ks * KSEG;
    const int c0   = k0 / 32;

    const float* xp = x + (size_t)(t0 + row) * DIM + k0 + grp * 8;

    f32x4 acc[4];
#pragma unroll
    for (int nt = 0; nt < 4; ++nt) acc[nt] = (f32x4){0.f, 0.f, 0.f, 0.f};

    f32x8 xc = *reinterpret_cast<const f32x8*>(xp);   // chunk 0
    f32x8 xn = xc;

    for (int c = 0; c < NCH; ++c) {
        // B frags for this chunk: 8 lane-consecutive dwordx4 (L2-hot)
        const size_t fo = ((size_t)(c0 + c) * 4 * 64 + lane) * 8;
        const short8 bh0 = *reinterpret_cast<const short8*>(Whf + fo);
        const short8 bh1 = *reinterpret_cast<const short8*>(Whf + fo + 512);
        const short8 bh2 = *reinterpret_cast<const short8*>(Whf + fo + 1024);
        const short8 bh3 = *reinterpret_cast<const short8*>(Whf + fo + 1536);
        const short8 bl0 = *reinterpret_cast<const short8*>(Wlf + fo);
        const short8 bl1 = *reinterpret_cast<const short8*>(Wlf + fo + 512);
        const short8 bl2 = *reinterpret_cast<const short8*>(Wlf + fo + 1024);
        const short8 bl3 = *reinterpret_cast<const short8*>(Wlf + fo + 1536);

        // prefetch next x chunk (HBM latency hides under convert+MFMA)
        if (c + 1 < NCH) xn = *reinterpret_cast<const f32x8*>(xp + (c + 1) * 32);

        // convert current x chunk to bf16 hi/lo fragments
        short8 ah, al;
#pragma unroll
        for (int j = 0; j < 8; ++j) {
            short hh, ll;
            bf16split(xc[j], hh, ll);
            ah[j] = hh; al[j] = ll;
        }

        acc[0] = __builtin_amdgcn_mfma_f32_16x16x32_bf16(ah, bh0, acc[0], 0, 0, 0);
        acc[1] = __builtin_amdgcn_mfma_f32_16x16x32_bf16(ah, bh1, acc[1], 0, 0, 0);
        acc[2] = __builtin_amdgcn_mfma_f32_16x16x32_bf16(ah, bh2, acc[2], 0, 0, 0);
        acc[3] = __builtin_amdgcn_mfma_f32_16x16x32_bf16(ah, bh3, acc[3], 0, 0, 0);
        acc[0] = __builtin_amdgcn_mfma_f32_16x16x32_bf16(al, bh0, acc[0], 0, 0, 0);
        acc[1] = __builtin_amdgcn_mfma_f32_16x16x32_bf16(al, bh1, acc[1], 0, 0, 0);
        acc[2] = __builtin_amdgcn_mfma_f32_16x16x32_bf16(al, bh2, acc[2], 0, 0, 0);
        acc[3] = __builtin_amdgcn_mfma_f32_16x16x32_bf16(al, bh3, acc[3], 0, 0, 0);
        acc[0] = __builtin_amdgcn_mfma_f32_16x16x32_bf16(ah, bl0, acc[0], 0, 0, 0);
        acc[1] = __builtin_amdgcn_mfma_f32_16x16x32_bf16(ah, bl1, acc[1], 0, 0, 0);
        acc[2] = __builtin_amdgcn_mfma_f32_16x16x32_bf16(ah, bl2, acc[2], 0, 0, 0);
        acc[3] = __builtin_amdgcn_mfma_f32_16x16x32_bf16(ah, bl3, acc[3], 0, 0, 0);
        acc[0] = __builtin_amdgcn_mfma_f32_16x16x32_bf16(al, bl0, acc[0], 0, 0, 0);
        acc[1] = __builtin_amdgcn_mfma_f32_16x16x32_bf16(al, bl1, acc[1], 0, 0, 0);
        acc[2] = __builtin_amdgcn_mfma_f32_16x16x32_bf16(al, bl2, acc[2], 0, 0, 0);
        acc[3] = __builtin_amdgcn_mfma_f32_16x16x32_bf16(al, bl3, acc[3], 0, 0, 0);

        xc = xn;
    }

    // D layout (m89-verified): col = lane&15, row = grp*4 + reg
    float* pp = part + ((size_t)ks * TOKENS + t0) * NEXP;
#pragma unroll
    for (int nt = 0; nt < 4; ++nt)
#pragma unroll
        for (int r = 0; r < 4; ++r)
            pp[(grp * 4 + r) * NEXP + nt * 16 + row] = acc[nt][r];
}

// ---- finalize: sum KS partials, softmax, top-2, scatter ----
template<int KS>
__global__ void tg_final(const float* __restrict__ part,
                         float* __restrict__ out_w, float* __restrict__ out_i) {
    int t = blockIdx.x * 256 + threadIdx.x;   // 0..8191

    float lg[NEXP];
    float m = -1e30f;
#pragma unroll
    for (int e = 0; e < NEXP; e += 4) {
        float4 s = *reinterpret_cast<const float4*>(part + (size_t)t * NEXP + e);
#pragma unroll
        for (int k = 1; k < KS; ++k) {
            float4 b = *reinterpret_cast<const float4*>(
                part + ((size_t)k * TOKENS + t) * NEXP + e);
            s.x += b.x; s.y += b.y; s.z += b.z; s.w += b.w;
        }
        lg[e+0] = s.x; lg[e+1] = s.y; lg[e+2] = s.z; lg[e+3] = s.w;
        m = fmaxf(m, fmaxf(fmaxf(s.x, s.y), fmaxf(s.z, s.w)));
    }
    float sum = 0.0f;
#pragma unroll
    for (int e = 0; e < NEXP; ++e) { lg[e] = expf(lg[e] - m); sum += lg[e]; }
    float inv = 1.0f / sum;

    // top-2 on probs; strict '>' scan => lower index wins ties (jax order)
    float v1 = -1.0f, v2 = -1.0f; int i1 = 0, i2 = 0;
#pragma unroll
    for (int e = 0; e < NEXP; ++e) {
        float p = lg[e] * inv;
        lg[e] = p;
        if (p > v1)      { v2 = v1; i2 = i1; v1 = p; i1 = e; }
        else if (p > v2) { v2 = p; i2 = e; }
    }

    float* dst = out_w + (size_t)t * NEXP;
#pragma unroll
    for (int e = 0; e < NEXP; e += 4) {
        float4 o;
        o.x = (e+0 == i1) ? v1 : (e+0 == i2) ? v2 : 0.0f;
        o.y = (e+1 == i1) ? v1 : (e+1 == i2) ? v2 : 0.0f;
        o.z = (e+2 == i1) ? v1 : (e+2 == i2) ? v2 : 0.0f;
        o.w = (e+3 == i1) ? v1 : (e+3 == i2) ? v2 : 0.0f;
        *reinterpret_cast<float4*>(dst + e) = o;
    }
    out_i[(size_t)t * 2 + 0] = (float)i1;
    out_i[(size_t)t * 2 + 1] = (float)i2;
}

extern "C" void kernel_launch(void* const* d_in, const int* in_sizes, int n_in,
                              void* d_out, int out_size, void* d_ws, size_t ws_size,
                              hipStream_t stream) {
    const float* x = (const float*)d_in[0];
    const float* W = (const float*)d_in[1];
    float* out_w = (float*)d_out;
    float* out_i = out_w + (size_t)TOKENS * NEXP;

    auto need = [](int ks) {
        return (size_t)ks * TOKENS * NEXP * 4 + 2 * FRAGS * sizeof(short);
    };
    const int KS = (ws_size >= need(8)) ? 8 : (ws_size >= need(4)) ? 4 : 2;

    float* part = (float*)d_ws;
    short* Whf  = (short*)((char*)d_ws + (size_t)KS * TOKENS * NEXP * 4);
    short* Wlf  = Whf + FRAGS;

    tg_prepw<<<dim3(128), dim3(256), 0, stream>>>(W, Whf, Wlf);
    if (KS == 8) {
        tg_mfma<8><<<dim3(128 * 8), dim3(256), 0, stream>>>(x, Whf, Wlf, part);
        tg_final<8><<<dim3(TOKENS / 256), dim3(256), 0, stream>>>(part, out_w, out_i);
    } else if (KS == 4) {
        tg_mfma<4><<<dim3(128 * 4), dim3(256), 0, stream>>>(x, Whf, Wlf, part);
        tg_final<4><<<dim3(TOKENS / 256), dim3(256), 0, stream>>>(part, out_w, out_i);
    } else {
        tg_mfma<2><<<dim3(128 * 2), dim3(256), 0, stream>>>(x, Whf, Wlf, part);
        tg_final<2><<<dim3(TOKENS / 256), dim3(256), 0, stream>>>(part, out_w, out_i);
    }
}

// Round 7
// 50.591 us; speedup vs baseline: 5.8750x; 1.4293x over previous
//
#include <hip/hip_runtime.h>
#include <math.h>

// TopKGate: logits = x @ W^T ; softmax ; top-2 ; scatter weights + indices(float).
// x: [8192,4096] f32, W: [64,4096] f32.
// d_out (f32 flat): weights [8192*64] then indices [8192*2] as floats.
//
// MFMA path: f32 as bf16 hi/lo split (hh+lh+hl+ll), logit err ~1e-4.
// Round-7 changes: (a) B-fragment register ping-pong + 2-deep x rotation so
// the K-loop never drains vmcnt to 0 (was: full B+x latency per chunk);
// (b) finalize is wave-per-token, lane=expert (coalesced 256-B partial reads,
// 2048 blocks) with butterfly-shuffle softmax/top-2.

#define TOKENS 8192
#define DIM    4096
#define NEXP   64
#define NCHW   (DIM / 32)          // 128 global k-chunks
#define FRAGS  ((size_t)NCHW * 4 * 64 * 8)   // 262144 shorts per array

typedef __attribute__((ext_vector_type(8))) short  short8;
typedef __attribute__((ext_vector_type(4))) float  f32x4;
typedef __attribute__((ext_vector_type(8))) float  f32x8;

__device__ __forceinline__ void bf16split(float v, short& hi, short& lo) {
    unsigned u = __float_as_uint(v);
    hi = (short)(u >> 16);
    float r = v - __uint_as_float(u & 0xffff0000u);
    lo = (short)(__float_as_uint(r) >> 16);
}

// ---- prep: W[64][4096] -> fragment-ordered bf16 hi/lo ----
// Whf[((c*4+nt)*64+lane)*8 + j] = bf16hi(W[e][k]), e = nt*16+(lane&15),
// k = c*32 + (lane>>4)*8 + j.  (same k-map as A: consistency trick)
__global__ void tg_prepw(const float* __restrict__ W,
                         short* __restrict__ Whf, short* __restrict__ Wlf) {
    int gid  = blockIdx.x * 256 + threadIdx.x;   // 32768 threads
    int c    = gid >> 8, rem = gid & 255;
    int nt   = rem >> 6, lane = rem & 63;
    int e    = nt * 16 + (lane & 15);
    int kb   = c * 32 + (lane >> 4) * 8;
    const float* wp = W + (size_t)e * DIM + kb;
    short8 h, l;
#pragma unroll
    for (int j = 0; j < 8; ++j) {
        short hh, ll;
        bf16split(wp[j], hh, ll);
        h[j] = hh; l[j] = ll;
    }
    size_t o = ((size_t)(c * 4 + nt) * 64 + lane) * 8;
    *reinterpret_cast<short8*>(Whf + o) = h;
    *reinterpret_cast<short8*>(Wlf + o) = l;
}

// ---- main: per wave 16 tokens x 64 experts, k-range KSEG ----
template<int KS>
__global__ __launch_bounds__(256, 2)
void tg_mfma(const float* __restrict__ x,
             const short* __restrict__ Whf, const short* __restrict__ Wlf,
             float* __restrict__ part) {
    constexpr int KSEG = DIM / KS;
    constexpr int NCH  = KSEG / 32;
    const int lane = threadIdx.x & 63;
    const int wave = threadIdx.x >> 6;
    const int mb   = blockIdx.x / KS;
    const int ks   = blockIdx.x % KS;
    const int t0   = mb * 64 + wave * 16;
    const int row  = lane & 15;          // A row (token) / B,D col (expert)
    const int grp  = lane >> 4;
    const int k0   = ks * KSEG;
    const int c0   = k0 / 32;

    const float* xp = x + (size_t)(t0 + row) * DIM + k0 + grp * 8;

    f32x4 acc[4];
#pragma unroll
    for (int nt = 0; nt < 4; ++nt) acc[nt] = (f32x4){0.f, 0.f, 0.f, 0.f};

    short8 bA[8], bB[8];
    auto loadB = [&](short8 (&b)[8], int c) {
        const size_t fo = (size_t)(c0 + c) * 2048 + (size_t)lane * 8;
        b[0] = *reinterpret_cast<const short8*>(Whf + fo);
        b[1] = *reinterpret_cast<const short8*>(Whf + fo + 512);
        b[2] = *reinterpret_cast<const short8*>(Whf + fo + 1024);
        b[3] = *reinterpret_cast<const short8*>(Whf + fo + 1536);
        b[4] = *reinterpret_cast<const short8*>(Wlf + fo);
        b[5] = *reinterpret_cast<const short8*>(Wlf + fo + 512);
        b[6] = *reinterpret_cast<const short8*>(Wlf + fo + 1024);
        b[7] = *reinterpret_cast<const short8*>(Wlf + fo + 1536);
    };
    auto convert = [&](const f32x8& xv, short8& ah, short8& al) {
#pragma unroll
        for (int j = 0; j < 8; ++j) {
            short hh, ll;
            bf16split(xv[j], hh, ll);
            ah[j] = hh; al[j] = ll;
        }
    };
    auto mfma16 = [&](const short8& ah, const short8& al, const short8 (&b)[8]) {
#pragma unroll
        for (int nt = 0; nt < 4; ++nt)
            acc[nt] = __builtin_amdgcn_mfma_f32_16x16x32_bf16(ah, b[nt], acc[nt], 0, 0, 0);
#pragma unroll
        for (int nt = 0; nt < 4; ++nt)
            acc[nt] = __builtin_amdgcn_mfma_f32_16x16x32_bf16(al, b[nt], acc[nt], 0, 0, 0);
#pragma unroll
        for (int nt = 0; nt < 4; ++nt)
            acc[nt] = __builtin_amdgcn_mfma_f32_16x16x32_bf16(ah, b[4 + nt], acc[nt], 0, 0, 0);
#pragma unroll
        for (int nt = 0; nt < 4; ++nt)
            acc[nt] = __builtin_amdgcn_mfma_f32_16x16x32_bf16(al, b[4 + nt], acc[nt], 0, 0, 0);
    };

    // prologue: B(0), x(0), x(1) in flight
    f32x8 xa = *reinterpret_cast<const f32x8*>(xp);
    f32x8 xb = *reinterpret_cast<const f32x8*>(xp + 32);
    loadB(bA, 0);

    short8 ah, al;
    for (int c = 0; c < NCH; c += 2) {
        loadB(bB, c + 1);                 // next chunk's B in flight
        convert(xa, ah, al);
        if (c + 2 < NCH) xa = *reinterpret_cast<const f32x8*>(xp + (c + 2) * 32);
        mfma16(ah, al, bA);               // waits only on bA (arrived last chunk)

        if (c + 2 < NCH) loadB(bA, c + 2);
        convert(xb, ah, al);
        if (c + 3 < NCH) xb = *reinterpret_cast<const f32x8*>(xp + (c + 3) * 32);
        mfma16(ah, al, bB);
    }

    // D layout (m89-verified): col = lane&15, row = grp*4 + reg
    float* pp = part + ((size_t)ks * TOKENS + t0) * NEXP;
#pragma unroll
    for (int nt = 0; nt < 4; ++nt)
#pragma unroll
        for (int r = 0; r < 4; ++r)
            pp[(grp * 4 + r) * NEXP + nt * 16 + row] = acc[nt][r];
}

// ---- finalize: wave-per-token, lane = expert; butterfly softmax + top-2 ----
template<int KS>
__global__ __launch_bounds__(256)
void tg_final(const float* __restrict__ part,
              float* __restrict__ out_w, float* __restrict__ out_i) {
    const int lane = threadIdx.x & 63;
    const int wv   = threadIdx.x >> 6;
    const int t    = blockIdx.x * 4 + wv;        // one token per wave

    float s = 0.0f;
#pragma unroll
    for (int k = 0; k < KS; ++k)                 // coalesced 256-B reads
        s += part[((size_t)k * TOKENS + t) * NEXP + lane];

    // softmax over 64 lanes (butterfly: all lanes converge bit-identically)
    float m = s;
#pragma unroll
    for (int o = 32; o > 0; o >>= 1) m = fmaxf(m, __shfl_xor(m, o));
    float p = expf(s - m);
    float sum = p;
#pragma unroll
    for (int o = 32; o > 0; o >>= 1) sum += __shfl_xor(sum, o);
    const float prob = p / sum;

    // top-1: max value, tie -> lower index (jax top_k order)
    float v1 = prob; int i1 = lane;
#pragma unroll
    for (int o = 32; o > 0; o >>= 1) {
        float ov = __shfl_xor(v1, o); int oi = __shfl_xor(i1, o);
        if (ov > v1 || (ov == v1 && oi < i1)) { v1 = ov; i1 = oi; }
    }
    // top-2: mask winner (probs >= 0 > -1)
    float v2 = (lane == i1) ? -1.0f : prob; int i2 = lane;
#pragma unroll
    for (int o = 32; o > 0; o >>= 1) {
        float ov = __shfl_xor(v2, o); int oi = __shfl_xor(i2, o);
        if (ov > v2 || (ov == v2 && oi < i2)) { v2 = ov; i2 = oi; }
    }

    out_w[(size_t)t * NEXP + lane] = (lane == i1) ? v1 : (lane == i2) ? v2 : 0.0f;
    if (lane == 0) {
        out_i[(size_t)t * 2 + 0] = (float)i1;
        out_i[(size_t)t * 2 + 1] = (float)i2;
    }
}

extern "C" void kernel_launch(void* const* d_in, const int* in_sizes, int n_in,
                              void* d_out, int out_size, void* d_ws, size_t ws_size,
                              hipStream_t stream) {
    const float* x = (const float*)d_in[0];
    const float* W = (const float*)d_in[1];
    float* out_w = (float*)d_out;
    float* out_i = out_w + (size_t)TOKENS * NEXP;

    auto need = [](int ks) {
        return (size_t)ks * TOKENS * NEXP * 4 + 2 * FRAGS * sizeof(short);
    };
    const int KS = (ws_size >= need(8)) ? 8 : (ws_size >= need(4)) ? 4 : 2;

    float* part = (float*)d_ws;
    short* Whf  = (short*)((char*)d_ws + (size_t)KS * TOKENS * NEXP * 4);
    short* Wlf  = Whf + FRAGS;

    tg_prepw<<<dim3(128), dim3(256), 0, stream>>>(W, Whf, Wlf);
    if (KS == 8) {
        tg_mfma<8><<<dim3(128 * 8), dim3(256), 0, stream>>>(x, Whf, Wlf, part);
        tg_final<8><<<dim3(TOKENS / 4), dim3(256), 0, stream>>>(part, out_w, out_i);
    } else if (KS == 4) {
        tg_mfma<4><<<dim3(128 * 4), dim3(256), 0, stream>>>(x, Whf, Wlf, part);
        tg_final<4><<<dim3(TOKENS / 4), dim3(256), 0, stream>>>(part, out_w, out_i);
    } else {
        tg_mfma<2><<<dim3(128 * 2), dim3(256), 0, stream>>>(x, Whf, Wlf, part);
        tg_final<2><<<dim3(TOKENS / 4), dim3(256), 0, stream>>>(part, out_w, out_i);
    }
}

// Round 8
// 50.213 us; speedup vs baseline: 5.9192x; 1.0075x over previous
//
#include <hip/hip_runtime.h>
#include <math.h>

// TopKGate: logits = x @ W^T ; softmax ; top-2 ; scatter weights + indices(float).
// x: [8192,4096] f32, W: [64,4096] f32.
// d_out (f32 flat): weights [8192*64] then indices [8192*2] as floats.
//
// MFMA path: f32 as bf16 hi/lo split (4 passes), logit err ~1e-4.
// Round-8: single fused main kernel. Block = 4 waves x 16 tokens, K split
// 4-ways in-block (KSEG=1024, NCH=32 chunks of 32), LDS reduce + butterfly
// softmax/top-2 epilogue (no global partials, no finalize kernel).
// Pipeline: x rotation depth 4 (~3 chunks slack vs HBM), B ping-pong
// consume-then-reload (~200 cyc slack vs L2). launch_bounds(256,3).

#define TOKENS 8192
#define DIM    4096
#define NEXP   64
#define NCHW   (DIM / 32)                    // 128 global k-chunks
#define FRAGS  ((size_t)NCHW * 4 * 64 * 8)   // 262144 shorts per array

#define BWAVES 4
#define KSEG   (DIM / BWAVES)                // 1024
#define NCH    (KSEG / 32)                   // 32 chunks per wave

typedef __attribute__((ext_vector_type(8))) short  short8;
typedef __attribute__((ext_vector_type(4))) float  f32x4;
typedef __attribute__((ext_vector_type(8))) float  f32x8;

__device__ __forceinline__ void bf16split(float v, short& hi, short& lo) {
    unsigned u = __float_as_uint(v);
    hi = (short)(u >> 16);
    float r = v - __uint_as_float(u & 0xffff0000u);
    lo = (short)(__float_as_uint(r) >> 16);
}

// ---- prep: W[64][4096] -> fragment-ordered bf16 hi/lo ----
// Whf[((c*4+nt)*64+lane)*8 + j] = bf16hi(W[e][k]), e = nt*16+(lane&15),
// k = c*32 + (lane>>4)*8 + j.  (same k-map as A: consistency trick)
__global__ void tg_prepw(const float* __restrict__ W,
                         short* __restrict__ Whf, short* __restrict__ Wlf) {
    int gid  = blockIdx.x * 256 + threadIdx.x;   // 32768 threads
    int c    = gid >> 8, rem = gid & 255;
    int nt   = rem >> 6, lane = rem & 63;
    int e    = nt * 16 + (lane & 15);
    int kb   = c * 32 + (lane >> 4) * 8;
    const float* wp = W + (size_t)e * DIM + kb;
    short8 h, l;
#pragma unroll
    for (int j = 0; j < 8; ++j) {
        short hh, ll;
        bf16split(wp[j], hh, ll);
        h[j] = hh; l[j] = ll;
    }
    size_t o = ((size_t)(c * 4 + nt) * 64 + lane) * 8;
    *reinterpret_cast<short8*>(Whf + o) = h;
    *reinterpret_cast<short8*>(Wlf + o) = l;
}

// ---- fused main: GEMM (bf16-split MFMA) + in-block reduce + softmax/top-2 ----
__global__ __launch_bounds__(256, 3)
void tg_fused(const float* __restrict__ x,
              const short* __restrict__ Whf, const short* __restrict__ Wlf,
              float* __restrict__ out_w, float* __restrict__ out_i) {
    __shared__ float red[BWAVES * 16 * NEXP];    // 16 KB

    const int lane = threadIdx.x & 63;
    const int wave = threadIdx.x >> 6;           // k-quarter
    const int t0   = blockIdx.x * 16;            // 16 tokens per block
    const int row  = lane & 15;                  // A row (token) / B,D col (expert)
    const int grp  = lane >> 4;
    const int c0   = wave * NCH;                 // global chunk base

    const float* xp = x + (size_t)(t0 + row) * DIM + wave * KSEG + grp * 8;

    f32x4 acc[4];
#pragma unroll
    for (int nt = 0; nt < 4; ++nt) acc[nt] = (f32x4){0.f, 0.f, 0.f, 0.f};

    short8 bA[8], bB[8];
    auto loadB = [&](short8 (&b)[8], int c) {
        const size_t fo = (size_t)(c0 + c) * 2048 + (size_t)lane * 8;
        b[0] = *reinterpret_cast<const short8*>(Whf + fo);
        b[1] = *reinterpret_cast<const short8*>(Whf + fo + 512);
        b[2] = *reinterpret_cast<const short8*>(Whf + fo + 1024);
        b[3] = *reinterpret_cast<const short8*>(Whf + fo + 1536);
        b[4] = *reinterpret_cast<const short8*>(Wlf + fo);
        b[5] = *reinterpret_cast<const short8*>(Wlf + fo + 512);
        b[6] = *reinterpret_cast<const short8*>(Wlf + fo + 1024);
        b[7] = *reinterpret_cast<const short8*>(Wlf + fo + 1536);
    };
    auto step = [&](const f32x8& xv, const short8 (&b)[8]) {
        short8 ah, al;
#pragma unroll
        for (int j = 0; j < 8; ++j) {
            short hh, ll;
            bf16split(xv[j], hh, ll);
            ah[j] = hh; al[j] = ll;
        }
#pragma unroll
        for (int nt = 0; nt < 4; ++nt)
            acc[nt] = __builtin_amdgcn_mfma_f32_16x16x32_bf16(ah, b[nt], acc[nt], 0, 0, 0);
#pragma unroll
        for (int nt = 0; nt < 4; ++nt)
            acc[nt] = __builtin_amdgcn_mfma_f32_16x16x32_bf16(al, b[nt], acc[nt], 0, 0, 0);
#pragma unroll
        for (int nt = 0; nt < 4; ++nt)
            acc[nt] = __builtin_amdgcn_mfma_f32_16x16x32_bf16(ah, b[4 + nt], acc[nt], 0, 0, 0);
#pragma unroll
        for (int nt = 0; nt < 4; ++nt)
            acc[nt] = __builtin_amdgcn_mfma_f32_16x16x32_bf16(al, b[4 + nt], acc[nt], 0, 0, 0);
    };

    // prologue: B(0),B(1) and x(0..3) in flight
    loadB(bA, 0);
    loadB(bB, 1);
    f32x8 xq0 = *reinterpret_cast<const f32x8*>(xp);
    f32x8 xq1 = *reinterpret_cast<const f32x8*>(xp + 32);
    f32x8 xq2 = *reinterpret_cast<const f32x8*>(xp + 64);
    f32x8 xq3 = *reinterpret_cast<const f32x8*>(xp + 96);

    for (int c = 0; c < NCH; c += 4) {
        step(xq0, bA);                                   // B(c)
        loadB(bA, c + 2);
        if (c + 4 < NCH) xq0 = *reinterpret_cast<const f32x8*>(xp + (c + 4) * 32);

        step(xq1, bB);                                   // B(c+1)
        loadB(bB, c + 3);
        if (c + 5 < NCH) xq1 = *reinterpret_cast<const f32x8*>(xp + (c + 5) * 32);

        step(xq2, bA);                                   // B(c+2)
        if (c + 4 < NCH) loadB(bA, c + 4);
        if (c + 6 < NCH) xq2 = *reinterpret_cast<const f32x8*>(xp + (c + 6) * 32);

        step(xq3, bB);                                   // B(c+3)
        if (c + 5 < NCH) loadB(bB, c + 5);
        if (c + 7 < NCH) xq3 = *reinterpret_cast<const f32x8*>(xp + (c + 7) * 32);
    }

    // ---- dump partials to LDS (D layout m89: col=lane&15, row=grp*4+reg) ----
    float* my = red + wave * 16 * NEXP;
#pragma unroll
    for (int nt = 0; nt < 4; ++nt)
#pragma unroll
        for (int r = 0; r < 4; ++r)
            my[(grp * 4 + r) * NEXP + nt * 16 + row] = acc[nt][r];
    __syncthreads();

    // ---- deterministic fixed-order reduce: 1024 logits, 256 threads x 4 ----
    const int tid = threadIdx.x;
#pragma unroll
    for (int q = 0; q < 4; ++q) {
        const int idx = q * 256 + tid;
        float s = red[idx] + red[1024 + idx] + red[2048 + idx] + red[3072 + idx];
        red[idx] = s;    // each idx owned by exactly one thread
    }
    __syncthreads();

    // ---- epilogue: 4 tokens per wave, lane = expert, butterfly softmax/top-2 ----
#pragma unroll
    for (int i = 0; i < 4; ++i) {
        const int tl = wave * 4 + i;
        const float s = red[tl * NEXP + lane];

        float m = s;
#pragma unroll
        for (int o = 32; o > 0; o >>= 1) m = fmaxf(m, __shfl_xor(m, o));
        float p = expf(s - m);
        float sum = p;
#pragma unroll
        for (int o = 32; o > 0; o >>= 1) sum += __shfl_xor(sum, o);
        const float prob = p / sum;

        // top-1: max value, tie -> lower index (jax top_k order)
        float v1 = prob; int i1 = lane;
#pragma unroll
        for (int o = 32; o > 0; o >>= 1) {
            float ov = __shfl_xor(v1, o); int oi = __shfl_xor(i1, o);
            if (ov > v1 || (ov == v1 && oi < i1)) { v1 = ov; i1 = oi; }
        }
        // top-2: mask winner (probs >= 0 > -1)
        float v2 = (lane == i1) ? -1.0f : prob; int i2 = lane;
#pragma unroll
        for (int o = 32; o > 0; o >>= 1) {
            float ov = __shfl_xor(v2, o); int oi = __shfl_xor(i2, o);
            if (ov > v2 || (ov == v2 && oi < i2)) { v2 = ov; i2 = oi; }
        }

        const int t = t0 + tl;
        out_w[(size_t)t * NEXP + lane] = (lane == i1) ? v1 : (lane == i2) ? v2 : 0.0f;
        if (lane == 0) {
            out_i[(size_t)t * 2 + 0] = (float)i1;
            out_i[(size_t)t * 2 + 1] = (float)i2;
        }
    }
}

extern "C" void kernel_launch(void* const* d_in, const int* in_sizes, int n_in,
                              void* d_out, int out_size, void* d_ws, size_t ws_size,
                              hipStream_t stream) {
    const float* x = (const float*)d_in[0];
    const float* W = (const float*)d_in[1];
    float* out_w = (float*)d_out;
    float* out_i = out_w + (size_t)TOKENS * NEXP;

    short* Whf = (short*)d_ws;                 // 512 KB
    short* Wlf = Whf + FRAGS;                  // 512 KB

    tg_prepw<<<dim3(128), dim3(256), 0, stream>>>(W, Whf, Wlf);
    tg_fused<<<dim3(TOKENS / 16), dim3(256), 0, stream>>>(x, Whf, Wlf, out_w, out_i);
}

// Round 9
// 49.038 us; speedup vs baseline: 6.0610x; 1.0240x over previous
//
#include <hip/hip_runtime.h>
#include <math.h>

// TopKGate: logits = x @ W^T ; softmax ; top-2 ; scatter weights + indices(float).
// x: [8192,4096] f32, W: [64,4096] f32.
// d_out (f32 flat): weights [8192*64] then indices [8192*2] as floats.
//
// MFMA path: f32 as bf16 hi/lo split, 3 passes (hh+lh+hl; ll ~2^-16 dropped).
// Round-9: 8-wave blocks, k-split 8 in-block (KSEG=512, NCH=16) -> 16 waves/CU
// (was 8; kernel was latency-bound at Occ 20.7%, VALU 8.5%, MFMA 8.3%).
// launch_bounds(512,4) caps VGPR at 128 so the ping-pong stays register-live
// (round-8's VGPR=72 proved the compiler serialized the pipeline).

#define TOKENS 8192
#define DIM    4096
#define NEXP   64
#define NCHW   (DIM / 32)                    // 128 global k-chunks
#define FRAGS  ((size_t)NCHW * 4 * 64 * 8)   // 262144 shorts per array

#define BWAVES 8
#define KSEG   (DIM / BWAVES)                // 512
#define NCH    (KSEG / 32)                   // 16 chunks per wave

typedef __attribute__((ext_vector_type(8))) short  short8;
typedef __attribute__((ext_vector_type(4))) float  f32x4;
typedef __attribute__((ext_vector_type(8))) float  f32x8;

__device__ __forceinline__ void bf16split(float v, short& hi, short& lo) {
    unsigned u = __float_as_uint(v);
    hi = (short)(u >> 16);
    float r = v - __uint_as_float(u & 0xffff0000u);
    lo = (short)(__float_as_uint(r) >> 16);
}

// ---- prep: W[64][4096] -> fragment-ordered bf16 hi/lo ----
// Whf[((c*4+nt)*64+lane)*8 + j] = bf16hi(W[e][k]), e = nt*16+(lane&15),
// k = c*32 + (lane>>4)*8 + j.  (same k-map as A: consistency trick)
__global__ void tg_prepw(const float* __restrict__ W,
                         short* __restrict__ Whf, short* __restrict__ Wlf) {
    int gid  = blockIdx.x * 256 + threadIdx.x;   // 32768 threads
    int c    = gid >> 8, rem = gid & 255;
    int nt   = rem >> 6, lane = rem & 63;
    int e    = nt * 16 + (lane & 15);
    int kb   = c * 32 + (lane >> 4) * 8;
    const float* wp = W + (size_t)e * DIM + kb;
    short8 h, l;
#pragma unroll
    for (int j = 0; j < 8; ++j) {
        short hh, ll;
        bf16split(wp[j], hh, ll);
        h[j] = hh; l[j] = ll;
    }
    size_t o = ((size_t)(c * 4 + nt) * 64 + lane) * 8;
    *reinterpret_cast<short8*>(Whf + o) = h;
    *reinterpret_cast<short8*>(Wlf + o) = l;
}

// ---- fused main: GEMM (bf16-split MFMA) + in-block reduce + softmax/top-2 ----
__global__ __launch_bounds__(512, 4)
void tg_fused(const float* __restrict__ x,
              const short* __restrict__ Whf, const short* __restrict__ Wlf,
              float* __restrict__ out_w, float* __restrict__ out_i) {
    __shared__ float red[BWAVES * 16 * NEXP];    // 32 KB

    const int lane = threadIdx.x & 63;
    const int wave = threadIdx.x >> 6;           // k-eighth, 0..7
    const int t0   = blockIdx.x * 16;            // 16 tokens per block
    const int row  = lane & 15;                  // A row (token) / B,D col (expert)
    const int grp  = lane >> 4;
    const int c0   = wave * NCH;                 // global chunk base

    const float* xp = x + (size_t)(t0 + row) * DIM + wave * KSEG + grp * 8;

    f32x4 acc[4];
#pragma unroll
    for (int nt = 0; nt < 4; ++nt) acc[nt] = (f32x4){0.f, 0.f, 0.f, 0.f};

    short8 bA[8], bB[8];
    auto loadB = [&](short8 (&b)[8], int c) {
        const size_t fo = (size_t)(c0 + c) * 2048 + (size_t)lane * 8;
        b[0] = *reinterpret_cast<const short8*>(Whf + fo);
        b[1] = *reinterpret_cast<const short8*>(Whf + fo + 512);
        b[2] = *reinterpret_cast<const short8*>(Whf + fo + 1024);
        b[3] = *reinterpret_cast<const short8*>(Whf + fo + 1536);
        b[4] = *reinterpret_cast<const short8*>(Wlf + fo);
        b[5] = *reinterpret_cast<const short8*>(Wlf + fo + 512);
        b[6] = *reinterpret_cast<const short8*>(Wlf + fo + 1024);
        b[7] = *reinterpret_cast<const short8*>(Wlf + fo + 1536);
    };
    auto step = [&](const f32x8& xv, const short8 (&b)[8]) {
        short8 ah, al;
#pragma unroll
        for (int j = 0; j < 8; ++j) {
            short hh, ll;
            bf16split(xv[j], hh, ll);
            ah[j] = hh; al[j] = ll;
        }
        // 3-pass split: hh + lh + hl (ll ~ 2^-16 relative, dropped)
#pragma unroll
        for (int nt = 0; nt < 4; ++nt)
            acc[nt] = __builtin_amdgcn_mfma_f32_16x16x32_bf16(ah, b[nt], acc[nt], 0, 0, 0);
#pragma unroll
        for (int nt = 0; nt < 4; ++nt)
            acc[nt] = __builtin_amdgcn_mfma_f32_16x16x32_bf16(al, b[nt], acc[nt], 0, 0, 0);
#pragma unroll
        for (int nt = 0; nt < 4; ++nt)
            acc[nt] = __builtin_amdgcn_mfma_f32_16x16x32_bf16(ah, b[4 + nt], acc[nt], 0, 0, 0);
    };

    // prologue: B(0),B(1) and x(0..3) in flight
    loadB(bA, 0);
    loadB(bB, 1);
    f32x8 xq0 = *reinterpret_cast<const f32x8*>(xp);
    f32x8 xq1 = *reinterpret_cast<const f32x8*>(xp + 32);
    f32x8 xq2 = *reinterpret_cast<const f32x8*>(xp + 64);
    f32x8 xq3 = *reinterpret_cast<const f32x8*>(xp + 96);

    for (int c = 0; c < NCH; c += 4) {
        step(xq0, bA);                                   // B(c)
        loadB(bA, c + 2);
        if (c + 4 < NCH) xq0 = *reinterpret_cast<const f32x8*>(xp + (c + 4) * 32);

        step(xq1, bB);                                   // B(c+1)
        loadB(bB, c + 3);
        if (c + 5 < NCH) xq1 = *reinterpret_cast<const f32x8*>(xp + (c + 5) * 32);

        step(xq2, bA);                                   // B(c+2)
        if (c + 4 < NCH) loadB(bA, c + 4);
        if (c + 6 < NCH) xq2 = *reinterpret_cast<const f32x8*>(xp + (c + 6) * 32);

        step(xq3, bB);                                   // B(c+3)
        if (c + 5 < NCH) loadB(bB, c + 5);
        if (c + 7 < NCH) xq3 = *reinterpret_cast<const f32x8*>(xp + (c + 7) * 32);
    }

    // ---- dump partials to LDS (D layout m89: col=lane&15, row=grp*4+reg) ----
    float* my = red + wave * 16 * NEXP;
#pragma unroll
    for (int nt = 0; nt < 4; ++nt)
#pragma unroll
        for (int r = 0; r < 4; ++r)
            my[(grp * 4 + r) * NEXP + nt * 16 + row] = acc[nt][r];
    __syncthreads();

    // ---- deterministic fixed-order reduce: 1024 logits, 512 threads x 2 ----
    const int tid = threadIdx.x;
#pragma unroll
    for (int q = 0; q < 2; ++q) {
        const int idx = q * 512 + tid;
        float s = red[idx];
#pragma unroll
        for (int w = 1; w < BWAVES; ++w) s += red[w * 1024 + idx];
        red[idx] = s;    // each idx owned by exactly one thread
    }
    __syncthreads();

    // ---- epilogue: 2 tokens per wave, lane = expert, butterfly softmax/top-2 ----
#pragma unroll
    for (int i = 0; i < 2; ++i) {
        const int tl = wave * 2 + i;
        const float s = red[tl * NEXP + lane];

        float m = s;
#pragma unroll
        for (int o = 32; o > 0; o >>= 1) m = fmaxf(m, __shfl_xor(m, o));
        float p = expf(s - m);
        float sum = p;
#pragma unroll
        for (int o = 32; o > 0; o >>= 1) sum += __shfl_xor(sum, o);
        const float prob = p / sum;

        // top-1: max value, tie -> lower index (jax top_k order)
        float v1 = prob; int i1 = lane;
#pragma unroll
        for (int o = 32; o > 0; o >>= 1) {
            float ov = __shfl_xor(v1, o); int oi = __shfl_xor(i1, o);
            if (ov > v1 || (ov == v1 && oi < i1)) { v1 = ov; i1 = oi; }
        }
        // top-2: mask winner (probs >= 0 > -1)
        float v2 = (lane == i1) ? -1.0f : prob; int i2 = lane;
#pragma unroll
        for (int o = 32; o > 0; o >>= 1) {
            float ov = __shfl_xor(v2, o); int oi = __shfl_xor(i2, o);
            if (ov > v2 || (ov == v2 && oi < i2)) { v2 = ov; i2 = oi; }
        }

        const int t = t0 + tl;
        out_w[(size_t)t * NEXP + lane] = (lane == i1) ? v1 : (lane == i2) ? v2 : 0.0f;
        if (lane == 0) {
            out_i[(size_t)t * 2 + 0] = (float)i1;
            out_i[(size_t)t * 2 + 1] = (float)i2;
        }
    }
}

extern "C" void kernel_launch(void* const* d_in, const int* in_sizes, int n_in,
                              void* d_out, int out_size, void* d_ws, size_t ws_size,
                              hipStream_t stream) {
    const float* x = (const float*)d_in[0];
    const float* W = (const float*)d_in[1];
    float* out_w = (float*)d_out;
    float* out_i = out_w + (size_t)TOKENS * NEXP;

    short* Whf = (short*)d_ws;                 // 512 KB
    short* Wlf = Whf + FRAGS;                  // 512 KB

    tg_prepw<<<dim3(128), dim3(256), 0, stream>>>(W, Whf, Wlf);
    tg_fused<<<dim3(TOKENS / 16), dim3(512), 0, stream>>>(x, Whf, Wlf, out_w, out_i);
}

// Round 10
// 44.864 us; speedup vs baseline: 6.6249x; 1.0930x over previous
//
#include <hip/hip_runtime.h>
#include <math.h>

// TopKGate: logits = x @ W^T ; softmax ; top-2 ; scatter weights + indices(float).
// x: [8192,4096] f32, W: [64,4096] f32.
// d_out (f32 flat): weights [8192*64] then indices [8192*2] as floats.
//
// MFMA path: f32 as bf16 hi/lo split, 3 passes (hh+lh+hl; ll ~2^-16 dropped).
// Round-10: pin the software pipeline with sched_barrier(0) fences. Rounds 8/9
// proved the compiler sinks all loads to their uses (VGPR=72 then 32 -> zero
// ILP, all pipes <9% busy). Fencing each load-issue cluster away from the
// compute cluster forces bA/bB/xq0-3 to stay register-live and in flight:
// B ping-pong at 2-phase distance (~L2 latency), x rotation at 4-phase
// distance (~L3/HBM latency). Geometry/reduce/epilogue unchanged (validated).

#define TOKENS 8192
#define DIM    4096
#define NEXP   64
#define NCHW   (DIM / 32)                    // 128 global k-chunks
#define FRAGS  ((size_t)NCHW * 4 * 64 * 8)   // 262144 shorts per array

#define BWAVES 8
#define KSEG   (DIM / BWAVES)                // 512
#define NCH    (KSEG / 32)                   // 16 chunks per wave

#define SBAR() __builtin_amdgcn_sched_barrier(0)

typedef __attribute__((ext_vector_type(8))) short  short8;
typedef __attribute__((ext_vector_type(4))) float  f32x4;
typedef __attribute__((ext_vector_type(8))) float  f32x8;

__device__ __forceinline__ void bf16split(float v, short& hi, short& lo) {
    unsigned u = __float_as_uint(v);
    hi = (short)(u >> 16);
    float r = v - __uint_as_float(u & 0xffff0000u);
    lo = (short)(__float_as_uint(r) >> 16);
}

// ---- prep: W[64][4096] -> fragment-ordered bf16 hi/lo ----
// Whf[((c*4+nt)*64+lane)*8 + j] = bf16hi(W[e][k]), e = nt*16+(lane&15),
// k = c*32 + (lane>>4)*8 + j.  (same k-map as A: consistency trick)
__global__ void tg_prepw(const float* __restrict__ W,
                         short* __restrict__ Whf, short* __restrict__ Wlf) {
    int gid  = blockIdx.x * 256 + threadIdx.x;   // 32768 threads
    int c    = gid >> 8, rem = gid & 255;
    int nt   = rem >> 6, lane = rem & 63;
    int e    = nt * 16 + (lane & 15);
    int kb   = c * 32 + (lane >> 4) * 8;
    const float* wp = W + (size_t)e * DIM + kb;
    short8 h, l;
#pragma unroll
    for (int j = 0; j < 8; ++j) {
        short hh, ll;
        bf16split(wp[j], hh, ll);
        h[j] = hh; l[j] = ll;
    }
    size_t o = ((size_t)(c * 4 + nt) * 64 + lane) * 8;
    *reinterpret_cast<short8*>(Whf + o) = h;
    *reinterpret_cast<short8*>(Wlf + o) = l;
}

// ---- fused main: GEMM (bf16-split MFMA) + in-block reduce + softmax/top-2 ----
__global__ __launch_bounds__(512, 4)
void tg_fused(const float* __restrict__ x,
              const short* __restrict__ Whf, const short* __restrict__ Wlf,
              float* __restrict__ out_w, float* __restrict__ out_i) {
    __shared__ float red[BWAVES * 16 * NEXP];    // 32 KB

    const int lane = threadIdx.x & 63;
    const int wave = threadIdx.x >> 6;           // k-eighth, 0..7
    const int t0   = blockIdx.x * 16;            // 16 tokens per block
    const int row  = lane & 15;                  // A row (token) / B,D col (expert)
    const int grp  = lane >> 4;
    const int c0   = wave * NCH;                 // global chunk base

    const float* xp = x + (size_t)(t0 + row) * DIM + wave * KSEG + grp * 8;

    f32x4 acc[4];
#pragma unroll
    for (int nt = 0; nt < 4; ++nt) acc[nt] = (f32x4){0.f, 0.f, 0.f, 0.f};

    short8 bA[8], bB[8];
    auto loadB = [&](short8 (&b)[8], int c) {
        const size_t fo = (size_t)(c0 + c) * 2048 + (size_t)lane * 8;
        b[0] = *reinterpret_cast<const short8*>(Whf + fo);
        b[1] = *reinterpret_cast<const short8*>(Whf + fo + 512);
        b[2] = *reinterpret_cast<const short8*>(Whf + fo + 1024);
        b[3] = *reinterpret_cast<const short8*>(Whf + fo + 1536);
        b[4] = *reinterpret_cast<const short8*>(Wlf + fo);
        b[5] = *reinterpret_cast<const short8*>(Wlf + fo + 512);
        b[6] = *reinterpret_cast<const short8*>(Wlf + fo + 1024);
        b[7] = *reinterpret_cast<const short8*>(Wlf + fo + 1536);
    };
    auto ldx = [&](int c) {
        return *reinterpret_cast<const f32x8*>(xp + c * 32);
    };
    auto step = [&](const f32x8& xv, const short8 (&b)[8]) {
        short8 ah, al;
#pragma unroll
        for (int j = 0; j < 8; ++j) {
            short hh, ll;
            bf16split(xv[j], hh, ll);
            ah[j] = hh; al[j] = ll;
        }
        // 3-pass split: hh + lh + hl (ll ~ 2^-16 relative, dropped)
#pragma unroll
        for (int nt = 0; nt < 4; ++nt)
            acc[nt] = __builtin_amdgcn_mfma_f32_16x16x32_bf16(ah, b[nt], acc[nt], 0, 0, 0);
#pragma unroll
        for (int nt = 0; nt < 4; ++nt)
            acc[nt] = __builtin_amdgcn_mfma_f32_16x16x32_bf16(al, b[nt], acc[nt], 0, 0, 0);
#pragma unroll
        for (int nt = 0; nt < 4; ++nt)
            acc[nt] = __builtin_amdgcn_mfma_f32_16x16x32_bf16(ah, b[4 + nt], acc[nt], 0, 0, 0);
    };

    // prologue: B(0),B(1) and x(0..3) in flight
    loadB(bA, 0);
    loadB(bB, 1);
    f32x8 xq0 = ldx(0);
    f32x8 xq1 = ldx(1);
    f32x8 xq2 = ldx(2);
    f32x8 xq3 = ldx(3);
    SBAR();

#pragma unroll
    for (int c = 0; c < NCH; c += 4) {
        step(xq0, bA);                                   // chunk c
        SBAR();
        loadB(bA, c + 2);                                // always < NCH
        if (c + 4 < NCH) xq0 = ldx(c + 4);
        SBAR();

        step(xq1, bB);                                   // chunk c+1
        SBAR();
        loadB(bB, c + 3);                                // always < NCH
        if (c + 5 < NCH) xq1 = ldx(c + 5);
        SBAR();

        step(xq2, bA);                                   // chunk c+2
        SBAR();
        if (c + 4 < NCH) loadB(bA, c + 4);
        if (c + 6 < NCH) xq2 = ldx(c + 6);
        SBAR();

        step(xq3, bB);                                   // chunk c+3
        SBAR();
        if (c + 5 < NCH) loadB(bB, c + 5);
        if (c + 7 < NCH) xq3 = ldx(c + 7);
        SBAR();
    }

    // ---- dump partials to LDS (D layout m89: col=lane&15, row=grp*4+reg) ----
    float* my = red + wave * 16 * NEXP;
#pragma unroll
    for (int nt = 0; nt < 4; ++nt)
#pragma unroll
        for (int r = 0; r < 4; ++r)
            my[(grp * 4 + r) * NEXP + nt * 16 + row] = acc[nt][r];
    __syncthreads();

    // ---- deterministic fixed-order reduce: 1024 logits, 512 threads x 2 ----
    const int tid = threadIdx.x;
#pragma unroll
    for (int q = 0; q < 2; ++q) {
        const int idx = q * 512 + tid;
        float s = red[idx];
#pragma unroll
        for (int w = 1; w < BWAVES; ++w) s += red[w * 1024 + idx];
        red[idx] = s;    // each idx owned by exactly one thread
    }
    __syncthreads();

    // ---- epilogue: 2 tokens per wave, lane = expert, butterfly softmax/top-2 ----
#pragma unroll
    for (int i = 0; i < 2; ++i) {
        const int tl = wave * 2 + i;
        const float s = red[tl * NEXP + lane];

        float m = s;
#pragma unroll
        for (int o = 32; o > 0; o >>= 1) m = fmaxf(m, __shfl_xor(m, o));
        float p = expf(s - m);
        float sum = p;
#pragma unroll
        for (int o = 32; o > 0; o >>= 1) sum += __shfl_xor(sum, o);
        const float prob = p / sum;

        // top-1: max value, tie -> lower index (jax top_k order)
        float v1 = prob; int i1 = lane;
#pragma unroll
        for (int o = 32; o > 0; o >>= 1) {
            float ov = __shfl_xor(v1, o); int oi = __shfl_xor(i1, o);
            if (ov > v1 || (ov == v1 && oi < i1)) { v1 = ov; i1 = oi; }
        }
        // top-2: mask winner (probs >= 0 > -1)
        float v2 = (lane == i1) ? -1.0f : prob; int i2 = lane;
#pragma unroll
        for (int o = 32; o > 0; o >>= 1) {
            float ov = __shfl_xor(v2, o); int oi = __shfl_xor(i2, o);
            if (ov > v2 || (ov == v2 && oi < i2)) { v2 = ov; i2 = oi; }
        }

        const int t = t0 + tl;
        out_w[(size_t)t * NEXP + lane] = (lane == i1) ? v1 : (lane == i2) ? v2 : 0.0f;
        if (lane == 0) {
            out_i[(size_t)t * 2 + 0] = (float)i1;
            out_i[(size_t)t * 2 + 1] = (float)i2;
        }
    }
}

extern "C" void kernel_launch(void* const* d_in, const int* in_sizes, int n_in,
                              void* d_out, int out_size, void* d_ws, size_t ws_size,
                              hipStream_t stream) {
    const float* x = (const float*)d_in[0];
    const float* W = (const float*)d_in[1];
    float* out_w = (float*)d_out;
    float* out_i = out_w + (size_t)TOKENS * NEXP;

    short* Whf = (short*)d_ws;                 // 512 KB
    short* Wlf = Whf + FRAGS;                  // 512 KB

    tg_prepw<<<dim3(128), dim3(256), 0, stream>>>(W, Whf, Wlf);
    tg_fused<<<dim3(TOKENS / 16), dim3(512), 0, stream>>>(x, Whf, Wlf, out_w, out_i);
}